// Round 7
// baseline (303.403 us; speedup 1.0000x reference)
//
#include <hip/hip_runtime.h>
#include <stdint.h>

#define C_IN 64
#define N_PT 4096
#define BN_TOT 32768          // B*N
#define KNB 20                // neighbors
#define KSZ 20                // kernel_size
#define C_OUT 64
#define BN_EPS 1e-5f
#define PPB 16                // points per k2 block (tile)
#define PELEM (KNB * KSZ)     // 400 floats of P per point

typedef __attribute__((address_space(3))) uint32_t* lds_ptr_t;
typedef const __attribute__((address_space(1))) uint32_t* gl_ptr_t;

__device__ __forceinline__ void glds16(const float* gp, float* lp) {
    // async global->LDS, 16B/lane; LDS dest = wave-uniform base + lane*16
    __builtin_amdgcn_global_load_lds((gl_ptr_t)(const void*)gp,
                                     (lds_ptr_t)(void*)lp, 16, 0, 0);
}

// ---------------------------------------------------------------------------
// K1: G[m][o] = sum_c conv_w[o][smap(c)] * feature[b][c][n],  m = b*N + n
//     1024 blocks (32-pt tiles) x 256 thr (4 waves); lane: p=lane&31,
//     ch-half=lane>>5; each lane 8 channels. LDS: fl 8KB + wl 16KB = 24KB
//     -> 6 blocks/CU = 24 waves/CU (r6 had only 2 blocks/CU).
//     Block 0 zeroes BN sums + counter (ws is 0xAA-poisoned each call).
// ---------------------------------------------------------------------------
__global__ __launch_bounds__(256) void k1_gemm(const float* __restrict__ feat,
                                               const float* __restrict__ conv_w,
                                               float* __restrict__ G,
                                               float* __restrict__ sums) {
    __shared__ float fl[C_IN * 32];              // [c][p], 8 KiB
    __shared__ float wl[C_IN * C_OUT];           // shuffled [c][o], 16 KiB
    const int b  = blockIdx.x >> 7;              // 8 batches x 128 tiles
    const int n0 = (blockIdx.x & 127) << 5;
    const int t  = threadIdx.x;

    if (blockIdx.x == 0 && t < 132) sums[t] = 0.f;

    // stage feature tile: 64c x 32p = 512 float4, 2/thread (coalesced)
    const float4* fsrc = reinterpret_cast<const float4*>(
        feat + (size_t)b * C_IN * N_PT + n0);
    float4* fl4 = reinterpret_cast<float4*>(fl);
#pragma unroll
    for (int j = 0; j < 2; ++j) {
        int idx = j * 256 + t;                   // 0..511
        int c = idx >> 3, p4 = idx & 7;          // 8 float4 per channel row
        fl4[idx] = fsrc[c * (N_PT / 4) + p4];
    }
    // stage weights with channel shuffle: wl[smap^{-1}(co)][o] = conv_w[o][co]
#pragma unroll
    for (int j = 0; j < 16; ++j) {
        int i = j * 256 + t;                     // 0..4095 coalesced read
        int o = i >> 6, co = i & 63;
        int cn = ((co & 3) << 4) | (co >> 2);    // smap^{-1}
        wl[cn * 64 + o] = conv_w[i];
    }
    __syncthreads();

    const int lane = t & 63;
    const int wid  = t >> 6;
    const int p    = lane & 31;
    const int ob   = wid * 16 + (lane >> 5) * 8; // 8 channels per lane

    float acc[8];
#pragma unroll
    for (int j = 0; j < 8; ++j) acc[j] = 0.f;

#pragma unroll 4
    for (int c = 0; c < C_IN; ++c) {
        float fc = fl[c * 32 + p];               // conflict-free (2-way bcast)
        float4 w0 = *reinterpret_cast<const float4*>(&wl[c * 64 + ob]);
        float4 w1 = *reinterpret_cast<const float4*>(&wl[c * 64 + ob + 4]);
        acc[0] += fc * w0.x; acc[1] += fc * w0.y;
        acc[2] += fc * w0.z; acc[3] += fc * w0.w;
        acc[4] += fc * w1.x; acc[5] += fc * w1.y;
        acc[6] += fc * w1.z; acc[7] += fc * w1.w;
    }

    size_t m = (size_t)b * N_PT + n0 + p;
    float4* gdst = reinterpret_cast<float4*>(G + m * 64 + ob);
    gdst[0] = make_float4(acc[0], acc[1], acc[2], acc[3]);
    gdst[1] = make_float4(acc[4], acc[5], acc[6], acc[7]);
}

// ---------------------------------------------------------------------------
// K2: per point n: out[o,s] = sum_k G[idx[n,k]][o] * P[n][k][s]
//     omax[n][o] = max_s + conv_b[o]; accumulate BN sum/sumsq.
//     2048 blocks x 256 thr, 16 pts/block (4/wave), lane = o.
//     P staged via global_load_lds (25 wave-instrs, zero ds_write issues);
//     FMA loop: s0..7 from LDS b128 broadcast (40 reads/pt, was 100+100 in r6
//     -> LDS-pipe floor 107us, the measured wall), s8..19 via uniform scalar
//     loads (L2-hot: the glds stage touched the lines one barrier earlier;
//     r1 lesson: COLD scalar P = 17K cyc/pt disaster).
//     idx via uniform s_load direct from global (no LDS staging).
// ---------------------------------------------------------------------------
__global__ __launch_bounds__(256) void k2_main(
        const int* __restrict__ nidx,
        const float* __restrict__ P,
        const float* __restrict__ G,
        const float* __restrict__ conv_b,
        float* __restrict__ omax,
        float* __restrict__ sums,
        unsigned* __restrict__ ctr,
        const float* __restrict__ bn_w,
        const float* __restrict__ bn_b,
        float* __restrict__ ss) {
    __shared__ float Pl[PPB * PELEM];            // 6400 floats, 25.6 KiB
    const int t    = threadIdx.x;
    const int lane = t & 63;
    const int wid  = t >> 6;
    const int tile = blockIdx.x;

    // stage P tile: 25 x glds16 wave-instrs (6400 floats exactly)
    const float* Pg = P + (size_t)tile * (PPB * PELEM);
    for (int i = wid; i < 25; i += 4)
        glds16(Pg + i * 256 + lane * 4, &Pl[i * 256]);
    __syncthreads();                             // drains vmcnt: stage done

    const float cb = conv_b[lane];
    const int pbase = wid * 4;
    float ls = 0.f, ls2 = 0.f;

    float g[2][KNB];                             // double-buffered gather rows
    {
        const int n0 = __builtin_amdgcn_readfirstlane(tile * PPB + pbase);
        const int* ip = nidx + (size_t)n0 * KNB; // uniform -> s_load
#pragma unroll
        for (int k = 0; k < KNB; ++k)
            g[0][k] = G[(size_t)ip[k] * 64 + lane];  // coalesced 256B row
    }

#pragma unroll
    for (int j = 0; j < 4; ++j) {
        const int cur = j & 1;                   // literal after unroll

        if (j < 3) {                             // prefetch next point's rows
            const int nn = __builtin_amdgcn_readfirstlane(tile * PPB + pbase + j + 1);
            const int* ip = nidx + (size_t)nn * KNB;
#pragma unroll
            for (int k = 0; k < KNB; ++k)
                g[cur ^ 1][k] = G[(size_t)ip[k] * 64 + lane];
        }

        const int n = __builtin_amdgcn_readfirstlane(tile * PPB + pbase + j);
        const float* pl = Pl + (pbase + j) * PELEM;      // LDS base (uniform)
        const float* pg = P + (size_t)n * PELEM;         // global scalar base

        float acc[KSZ];
#pragma unroll
        for (int s = 0; s < KSZ; ++s) acc[s] = 0.f;

#pragma unroll 4
        for (int k = 0; k < KNB; ++k) {
            const float gk = g[cur][k];
            float4 a  = *reinterpret_cast<const float4*>(pl + k * KSZ);      // s0..3  LDS
            float4 bb = *reinterpret_cast<const float4*>(pl + k * KSZ + 4);  // s4..7  LDS
            float4 c0 = *reinterpret_cast<const float4*>(pg + k * KSZ + 8);  // s8..11 scalar
            float4 c1 = *reinterpret_cast<const float4*>(pg + k * KSZ + 12); // s12..15 scalar
            float4 c2 = *reinterpret_cast<const float4*>(pg + k * KSZ + 16); // s16..19 scalar
            acc[0]  += gk * a.x;  acc[1]  += gk * a.y;
            acc[2]  += gk * a.z;  acc[3]  += gk * a.w;
            acc[4]  += gk * bb.x; acc[5]  += gk * bb.y;
            acc[6]  += gk * bb.z; acc[7]  += gk * bb.w;
            acc[8]  += gk * c0.x; acc[9]  += gk * c0.y;
            acc[10] += gk * c0.z; acc[11] += gk * c0.w;
            acc[12] += gk * c1.x; acc[13] += gk * c1.y;
            acc[14] += gk * c1.z; acc[15] += gk * c1.w;
            acc[16] += gk * c2.x; acc[17] += gk * c2.y;
            acc[18] += gk * c2.z; acc[19] += gk * c2.w;
        }

        float mx = acc[0];
#pragma unroll
        for (int s = 1; s < KSZ; ++s) mx = fmaxf(mx, acc[s]);
        mx += cb;
        omax[(size_t)n * 64 + lane] = mx;        // coalesced
        ls += mx;
        ls2 += mx * mx;
    }

    // block-level BN partial reduction (reuse Pl after barrier)
    __syncthreads();                             // all Pl reads done
    float* r1 = Pl;                              // [4][64]
    float* r2 = Pl + 256;
    r1[wid * 64 + lane] = ls;
    r2[wid * 64 + lane] = ls2;
    __syncthreads();
    if (wid == 0) {
        float a  = r1[lane] + r1[64 + lane] + r1[128 + lane] + r1[192 + lane];
        float c2 = r2[lane] + r2[64 + lane] + r2[128 + lane] + r2[192 + lane];
        atomicAdd(&sums[lane], a);
        atomicAdd(&sums[64 + lane], c2);
    }
    __syncthreads();

    // last-block BN stats finalize (fused k3)
    __shared__ bool lastBlk;
    if (t == 0) {
        __threadfence();
        lastBlk = (atomicAdd(ctr, 1u) == (unsigned)(gridDim.x - 1));
    }
    __syncthreads();
    if (lastBlk && t < 64) {
        float s1 = atomicAdd(&sums[t], 0.f);     // coherent read
        float s2 = atomicAdd(&sums[64 + t], 0.f);
        const float inv = 1.f / (float)BN_TOT;
        float mean = s1 * inv;
        float var  = s2 * inv - mean * mean;
        float rstd = rsqrtf(var + BN_EPS);
        float sc = rstd * bn_w[t];
        ss[t] = sc;
        ss[64 + t] = bn_b[t] - mean * sc;
    }
}

// ---------------------------------------------------------------------------
// K4: apply BN + transpose [BN,64] -> [B,64,N]
//     512 blocks x 512 threads; wave w handles channels [w*8, w*8+8).
// ---------------------------------------------------------------------------
__global__ __launch_bounds__(512) void k4_apply(const float* __restrict__ omax,
                                                const float* __restrict__ ss,
                                                float* __restrict__ out) {
    const int b  = blockIdx.x >> 6;
    const int n0 = (blockIdx.x & 63) << 6;
    const int t  = threadIdx.x;
    const int nl = t & 63;
    const int ob = (t >> 6) << 3;

    const size_t m = (size_t)b * N_PT + n0 + nl;
    const float4* src = reinterpret_cast<const float4*>(omax + m * 64 + ob);
    float v[8];
    float4 x0 = src[0], x1 = src[1];
    v[0] = x0.x; v[1] = x0.y; v[2] = x0.z; v[3] = x0.w;
    v[4] = x1.x; v[5] = x1.y; v[6] = x1.z; v[7] = x1.w;
#pragma unroll
    for (int j = 0; j < 8; ++j) {
        int o = ob + j;
        float sc = ss[o];
        float sh = ss[64 + o];
        out[(size_t)b * C_OUT * N_PT + (size_t)o * N_PT + n0 + nl] =
            v[j] * sc + sh;                      // coalesced 256B store
    }
}

// ---------------------------------------------------------------------------
extern "C" void kernel_launch(void* const* d_in, const int* in_sizes, int n_in,
                              void* d_out, int out_size, void* d_ws, size_t ws_size,
                              hipStream_t stream) {
    const float* feature = (const float*)d_in[0];
    const int*   nidx    = (const int*)d_in[1];
    const float* perm    = (const float*)d_in[2];
    const float* conv_w  = (const float*)d_in[3];
    const float* conv_b  = (const float*)d_in[4];
    const float* bn_w    = (const float*)d_in[5];
    const float* bn_b    = (const float*)d_in[6];
    float* out = (float*)d_out;

    char* ws = (char*)d_ws;
    float* G    = (float*)ws;                                   // 8 MiB
    float* OM   = (float*)(ws + (size_t)8 * 1024 * 1024);       // 8 MiB
    float* SUMS = (float*)(ws + (size_t)16 * 1024 * 1024);      // [0..127]
    unsigned* CTR = (unsigned*)(SUMS + 128);                    // [128]
    float* SS   = SUMS + 132;                                   // 128 floats

    k1_gemm<<<1024, 256, 0, stream>>>(feature, conv_w, G, SUMS);
    k2_main<<<BN_TOT / PPB, 256, 0, stream>>>(nidx, perm, G, conv_b, OM, SUMS,
                                              CTR, bn_w, bn_b, SS);
    k4_apply<<<512, 512, 0, stream>>>(OM, SS, out);
}